// Round 2
// baseline (274.866 us; speedup 1.0000x reference)
//
#include <hip/hip_runtime.h>

#define V_N 5023
#define NC_REAL 15069      // V*3
#define NC_PAD 15168       // 79*64*3 (vertex-tile padded)
#define KTOT 192           // 150 betas + 2 pad + 36 pose_feature + 4 pad
#define B_N 1024

__device__ __forceinline__ float bf2f(unsigned short u) {
  union { unsigned int i; float f; } x; x.i = ((unsigned int)u) << 16; return x.f;
}
__device__ __forceinline__ unsigned short f2bf(float f) {
  union { float f; unsigned int i; } x; x.f = f;
  unsigned int u = x.i;
  u = (u + 0x7FFFu + ((u >> 16) & 1u)) >> 16;
  return (unsigned short)u;
}

// ---------------- transpose shapedirs (vc-major-k -> k-major-vc), f32 -> bf16, zero-pad ----------------
// sd: (15069, 150) f32 (element (vc,k) at vc*150+k) -> sdT rows 0..151 of (192, 15168) bf16
__global__ void k_sd_transpose(const float* __restrict__ sd,
                               unsigned short* __restrict__ sdT) {
  __shared__ unsigned short tile[64][153];
  int vc0 = blockIdx.x * 64;         // grid 237 -> covers 15168 cols
  int t = threadIdx.x;
  int col = t >> 2, q = t & 3;
  int vc = vc0 + col;
  #pragma unroll
  for (int i = 0; i < 38; ++i) {
    int k = q * 38 + i;              // 0..151
    unsigned short val = 0;
    if (k < 150 && vc < NC_REAL) val = f2bf(sd[vc * 150 + k]);
    tile[col][k] = val;
  }
  __syncthreads();
  for (int u = t; u < 152 * 32; u += 256) {
    int row = u >> 5, cp = u & 31;
    unsigned int lo = tile[2 * cp][row], hi = tile[2 * cp + 1][row];
    ((unsigned int*)sdT)[row * (NC_PAD / 2) + (vc0 >> 1) + cp] = lo | (hi << 16);
  }
}

// posedirs (36, 15069) f32 -> bf16 sdT rows 152..191 (rows 188..191 zero), zero-pad cols
__global__ void k_pd_copy(const float* __restrict__ pd,
                          unsigned short* __restrict__ sdT) {
  int g = blockIdx.x * 256 + threadIdx.x;   // grid 2370 -> 40*15168 exact
  int rr = g / NC_PAD, vc = g - rr * NC_PAD;
  unsigned short val = 0;
  if (rr < 36 && vc < NC_REAL) val = f2bf(pd[rr * NC_REAL + vc]);
  sdT[(152 + rr) * NC_PAD + vc] = val;
}

// ---------------- JS = Jreg @ shapedirs (5,3,150), Jt = Jreg @ v_template (5,3) ----------------
__global__ void k_js(const float* __restrict__ jreg,
                     const float* __restrict__ sd,
                     const float* __restrict__ vt,
                     float* __restrict__ JS, float* __restrict__ Jt) {
  int blk = blockIdx.x;   // 0..449: (c,l) over shapedirs; 450..452: c over v_template
  int t = threadIdx.x;
  float acc[5] = {0.f, 0.f, 0.f, 0.f, 0.f};
  if (blk < 450) {
    int c = blk / 150, l = blk - (blk / 150) * 150;
    for (int v = t; v < V_N; v += 256) {
      float s = sd[(v * 3 + c) * 150 + l];
      #pragma unroll
      for (int j = 0; j < 5; j++) acc[j] += jreg[j * V_N + v] * s;
    }
  } else {
    int c = blk - 450;
    for (int v = t; v < V_N; v += 256) {
      float s = vt[v * 3 + c];
      #pragma unroll
      for (int j = 0; j < 5; j++) acc[j] += jreg[j * V_N + v] * s;
    }
  }
  __shared__ float red[5][4];
  #pragma unroll
  for (int j = 0; j < 5; j++) {
    float x = acc[j];
    for (int off = 32; off > 0; off >>= 1) x += __shfl_down(x, off);
    if ((t & 63) == 0) red[j][t >> 6] = x;
  }
  __syncthreads();
  if (t < 5) {
    float s = red[t][0] + red[t][1] + red[t][2] + red[t][3];
    if (blk < 450) {
      int c = blk / 150, l = blk - (blk / 150) * 150;
      JS[(t * 3 + c) * 150 + l] = s;
    } else {
      Jt[t * 3 + (blk - 450)] = s;
    }
  }
}

// ---------------- betasT rows 0..151: transposed (k-major) f32 betas ----------------
__global__ void k_betasT(const float* __restrict__ shp,
                         const float* __restrict__ expr,
                         float* __restrict__ betasT) {
  int g = blockIdx.x * 256 + threadIdx.x;   // grid 608 -> 152*1024 exact
  int k = g >> 10, b = g & 1023;
  float v = 0.f;
  if (k < 100) v = shp[b * 100 + k];
  else if (k < 150) v = expr[b * 50 + (k - 100)];
  betasT[g] = v;
}

// ---------------- per-batch: rodrigues, joints, chain, rel transforms, pose feature ----------------
__device__ __forceinline__ void rodrigues(const float* p, float* R) {
  float x = p[0], y = p[1], z = p[2];
  float xa = x + 1e-8f, ya = y + 1e-8f, za = z + 1e-8f;
  float angle = sqrtf(xa * xa + ya * ya + za * za);
  float inv = 1.0f / angle;
  float rx = x * inv, ry = y * inv, rz = z * inv;
  float c = cosf(angle), s = sinf(angle), t1 = 1.0f - c;
  float K[9] = {0.f, -rz, ry, rz, 0.f, -rx, -ry, rx, 0.f};
  float KK[9];
  #pragma unroll
  for (int i = 0; i < 3; i++)
    #pragma unroll
    for (int j = 0; j < 3; j++) {
      float a = 0.f;
      #pragma unroll
      for (int k = 0; k < 3; k++) a += K[i * 3 + k] * K[k * 3 + j];
      KK[i * 3 + j] = a;
    }
  #pragma unroll
  for (int i = 0; i < 9; i++) R[i] = s * K[i] + t1 * KK[i];
  R[0] += 1.f; R[4] += 1.f; R[8] += 1.f;
}

__global__ void k_pose(const float* __restrict__ pose,
                       const float* __restrict__ neck,
                       const float* __restrict__ eye,
                       const float* __restrict__ JS,
                       const float* __restrict__ Jt,
                       float* __restrict__ betasT,
                       float* __restrict__ relT) {
  int b = blockIdx.x * 256 + threadIdx.x;
  if (b >= B_N) return;
  float fp[15];
  fp[0] = pose[b * 6 + 0]; fp[1] = pose[b * 6 + 1]; fp[2] = pose[b * 6 + 2];
  fp[3] = neck[0]; fp[4] = neck[1]; fp[5] = neck[2];
  fp[6] = pose[b * 6 + 3]; fp[7] = pose[b * 6 + 4]; fp[8] = pose[b * 6 + 5];
  #pragma unroll
  for (int i = 0; i < 6; i++) fp[9 + i] = eye[i];
  float R[5][9];
  #pragma unroll
  for (int j = 0; j < 5; j++) rodrigues(&fp[j * 3], R[j]);
  float J[5][3];
  #pragma unroll
  for (int j = 0; j < 5; j++)
    #pragma unroll
    for (int c = 0; c < 3; c++) J[j][c] = Jt[j * 3 + c];
  for (int k = 0; k < 150; k++) {
    float be = betasT[k * B_N + b];   // coalesced across lanes
    #pragma unroll
    for (int j = 0; j < 5; j++)
      #pragma unroll
      for (int c = 0; c < 3; c++) J[j][c] += be * JS[(j * 3 + c) * 150 + k];
  }
  float rel[5][3];
  #pragma unroll
  for (int c = 0; c < 3; c++) {
    rel[0][c] = J[0][c];
    rel[1][c] = J[1][c] - J[0][c];
    rel[2][c] = J[2][c] - J[1][c];
    rel[3][c] = J[3][c] - J[1][c];
    rel[4][c] = J[4][c] - J[1][c];
  }
  float GR[5][9], Gt[5][3];
  #pragma unroll
  for (int i = 0; i < 9; i++) GR[0][i] = R[0][i];
  #pragma unroll
  for (int c = 0; c < 3; c++) Gt[0][c] = rel[0][c];
  const int parent[5] = {0, 0, 1, 1, 1};
  #pragma unroll
  for (int j = 1; j < 5; j++) {
    int p = parent[j];
    #pragma unroll
    for (int r = 0; r < 3; r++)
      #pragma unroll
      for (int c = 0; c < 3; c++) {
        float a = 0.f;
        #pragma unroll
        for (int k = 0; k < 3; k++) a += GR[p][r * 3 + k] * R[j][k * 3 + c];
        GR[j][r * 3 + c] = a;
      }
    #pragma unroll
    for (int r = 0; r < 3; r++) {
      float a = Gt[p][r];
      #pragma unroll
      for (int k = 0; k < 3; k++) a += GR[p][r * 3 + k] * rel[j][k];
      Gt[j][r] = a;
    }
  }
  // rel transforms: R = GR, t = Gt - GR*J ; layout [j][r][4]
  #pragma unroll
  for (int j = 0; j < 5; j++) {
    #pragma unroll
    for (int r = 0; r < 3; r++) {
      float a = 0.f;
      #pragma unroll
      for (int k = 0; k < 3; k++) a += GR[j][r * 3 + k] * J[j][k];
      float tr = Gt[j][r] - a;
      #pragma unroll
      for (int c = 0; c < 3; c++) relT[b * 60 + j * 12 + r * 4 + c] = GR[j][r * 3 + c];
      relT[b * 60 + j * 12 + r * 4 + 3] = tr;
    }
  }
  // pose feature -> betasT rows 152..187 (rows 188..191 zero)
  #pragma unroll
  for (int j = 1; j < 5; j++)
    #pragma unroll
    for (int r = 0; r < 3; r++)
      #pragma unroll
      for (int c = 0; c < 3; c++) {
        int kk = (j - 1) * 9 + r * 3 + c;
        betasT[(152 + kk) * B_N + b] = R[j][r * 3 + c] - ((r == c) ? 1.f : 0.f);
      }
  #pragma unroll
  for (int kk = 36; kk < 40; kk++) betasT[(152 + kk) * B_N + b] = 0.f;
}

// ---------------- main: fused K=192 GEMM + LBS skinning epilogue ----------------
// block: 64 batches x 64 vertices; thread: 8 batches x 2 adjacent vertices x 3 coords = 48 acc
__global__ __launch_bounds__(256) void k_main(
    const unsigned short* __restrict__ sdT,
    const float* __restrict__ betasT,
    const float* __restrict__ relT,
    const float* __restrict__ vt,
    const float* __restrict__ lbsw,
    float* __restrict__ out) {
  __shared__ float sBet[8][64];
  __shared__ float sSd[8][3][64];   // [k][coord][vertex_local]
  int t = threadIdx.x;
  int bg = t >> 5;                  // 0..7
  int tv = t & 31;                  // 0..31
  int v0 = blockIdx.x * 64;
  int b0 = blockIdx.y * 64;
  float acc[8][2][3];
  #pragma unroll
  for (int a = 0; a < 8; a++)
    #pragma unroll
    for (int b2 = 0; b2 < 2; b2++)
      #pragma unroll
      for (int c = 0; c < 3; c++) acc[a][b2][c] = 0.f;
  const unsigned int* sdT32 = (const unsigned int*)sdT;
  for (int kc = 0; kc < 24; kc++) {
    int k0 = kc * 8;
    {
      int f = t;
      #pragma unroll
      for (int i = 0; i < 2; i++, f += 256) {
        int r = f >> 6, c = f & 63;
        sBet[r][c] = betasT[(k0 + r) * B_N + b0 + c];
      }
      int u = t;
      #pragma unroll
      for (int i = 0; i < 3; i++, u += 256) {
        int r = u / 96, c2 = u - (u / 96) * 96;
        unsigned int w = sdT32[(k0 + r) * (NC_PAD / 2) + blockIdx.x * 96 + c2];
        int vcA = 2 * c2, vcB = vcA + 1;
        sSd[r][vcA % 3][vcA / 3] = bf2f((unsigned short)(w & 0xFFFFu));
        sSd[r][vcB % 3][vcB / 3] = bf2f((unsigned short)(w >> 16));
      }
    }
    __syncthreads();
    #pragma unroll
    for (int r = 0; r < 8; r++) {
      float4 be0 = *(const float4*)&sBet[r][bg * 8];
      float4 be1 = *(const float4*)&sBet[r][bg * 8 + 4];
      float2 sx = *(const float2*)&sSd[r][0][2 * tv];
      float2 sy = *(const float2*)&sSd[r][1][2 * tv];
      float2 sz = *(const float2*)&sSd[r][2][2 * tv];
      float be[8] = {be0.x, be0.y, be0.z, be0.w, be1.x, be1.y, be1.z, be1.w};
      #pragma unroll
      for (int bi = 0; bi < 8; bi++) {
        acc[bi][0][0] += be[bi] * sx.x;
        acc[bi][1][0] += be[bi] * sx.y;
        acc[bi][0][1] += be[bi] * sy.x;
        acc[bi][1][1] += be[bi] * sy.y;
        acc[bi][0][2] += be[bi] * sz.x;
        acc[bi][1][2] += be[bi] * sz.y;
      }
    }
    __syncthreads();
  }
  // epilogue: v_posed = acc + v_template; skinning blend; f32 store
  int vA = v0 + 2 * tv, vB = vA + 1;
  bool okA = vA < V_N, okB = vB < V_N;
  float vtA[3] = {0.f, 0.f, 0.f}, vtB[3] = {0.f, 0.f, 0.f};
  float wA[5] = {0.f, 0.f, 0.f, 0.f, 0.f}, wB[5] = {0.f, 0.f, 0.f, 0.f, 0.f};
  if (okA) {
    #pragma unroll
    for (int c = 0; c < 3; c++) vtA[c] = vt[vA * 3 + c];
    #pragma unroll
    for (int j = 0; j < 5; j++) wA[j] = lbsw[vA * 5 + j];
  }
  if (okB) {
    #pragma unroll
    for (int c = 0; c < 3; c++) vtB[c] = vt[vB * 3 + c];
    #pragma unroll
    for (int j = 0; j < 5; j++) wB[j] = lbsw[vB * 5 + j];
  }
  #pragma unroll
  for (int bi = 0; bi < 8; bi++) {
    int b = b0 + bg * 8 + bi;
    const float4* rT = (const float4*)(relT + b * 60);
    float pA0 = acc[bi][0][0] + vtA[0], pA1 = acc[bi][0][1] + vtA[1], pA2 = acc[bi][0][2] + vtA[2];
    float pB0 = acc[bi][1][0] + vtB[0], pB1 = acc[bi][1][1] + vtB[1], pB2 = acc[bi][1][2] + vtB[2];
    float oA0 = 0.f, oA1 = 0.f, oA2 = 0.f, oB0 = 0.f, oB1 = 0.f, oB2 = 0.f;
    #pragma unroll
    for (int j = 0; j < 5; j++) {
      float4 m0 = rT[j * 3 + 0], m1 = rT[j * 3 + 1], m2 = rT[j * 3 + 2];
      oA0 += wA[j] * (m0.x * pA0 + m0.y * pA1 + m0.z * pA2 + m0.w);
      oA1 += wA[j] * (m1.x * pA0 + m1.y * pA1 + m1.z * pA2 + m1.w);
      oA2 += wA[j] * (m2.x * pA0 + m2.y * pA1 + m2.z * pA2 + m2.w);
      oB0 += wB[j] * (m0.x * pB0 + m0.y * pB1 + m0.z * pB2 + m0.w);
      oB1 += wB[j] * (m1.x * pB0 + m1.y * pB1 + m1.z * pB2 + m1.w);
      oB2 += wB[j] * (m2.x * pB0 + m2.y * pB1 + m2.z * pB2 + m2.w);
    }
    if (okA) {
      size_t off = (size_t)b * NC_REAL + (size_t)vA * 3;
      out[off] = oA0; out[off + 1] = oA1; out[off + 2] = oA2;
    }
    if (okB) {
      size_t off = (size_t)b * NC_REAL + (size_t)vB * 3;
      out[off] = oB0; out[off + 1] = oB1; out[off + 2] = oB2;
    }
  }
}

// ---------------- landmarks gather ----------------
__global__ void k_lmk(const float* __restrict__ verts,
                      const int* __restrict__ land,
                      float* __restrict__ lm) {
  int g = blockIdx.x * 256 + threadIdx.x;   // grid 816 -> 1024*68*3 exact
  int b = g / 204;
  int r = g - b * 204;
  int i = r / 3, c = r - i * 3;
  lm[g] = verts[(size_t)b * NC_REAL + (size_t)land[i] * 3 + c];
}

extern "C" void kernel_launch(void* const* d_in, const int* in_sizes, int n_in,
                              void* d_out, int out_size, void* d_ws, size_t ws_size,
                              hipStream_t stream) {
  const float* shp  = (const float*)d_in[0];
  const float* expr = (const float*)d_in[1];
  const float* pose = (const float*)d_in[2];
  const int*   land = (const int*)d_in[3];
  const float* vt   = (const float*)d_in[4];
  const float* sd   = (const float*)d_in[5];
  const float* pd   = (const float*)d_in[6];
  const float* jreg = (const float*)d_in[7];
  const float* lbsw = (const float*)d_in[8];
  const float* eye  = (const float*)d_in[9];
  const float* neck = (const float*)d_in[10];
  char* ws = (char*)d_ws;
  // ws layout (16B-aligned): sdT 5,824,512 | betasT 786,432 | JS 9,216 | Jt 64 | relT 245,760
  unsigned short* sdT = (unsigned short*)(ws + 0);
  float* betasT = (float*)(ws + 5824512);
  float* JS     = (float*)(ws + 6610944);
  float* Jt     = (float*)(ws + 6620160);
  float* relT   = (float*)(ws + 6620224);
  float* outv = (float*)d_out;
  float* outl = outv + (size_t)B_N * NC_REAL;

  hipLaunchKernelGGL(k_sd_transpose, dim3(237), dim3(256), 0, stream, sd, sdT);
  hipLaunchKernelGGL(k_pd_copy, dim3(2370), dim3(256), 0, stream, pd, sdT);
  hipLaunchKernelGGL(k_js, dim3(453), dim3(256), 0, stream, jreg, sd, vt, JS, Jt);
  hipLaunchKernelGGL(k_betasT, dim3(608), dim3(256), 0, stream, shp, expr, betasT);
  hipLaunchKernelGGL(k_pose, dim3(4), dim3(256), 0, stream, pose, neck, eye, JS, Jt, betasT, relT);
  hipLaunchKernelGGL(k_main, dim3(79, 16), dim3(256), 0, stream, sdT, betasT, relT, vt, lbsw, outv);
  hipLaunchKernelGGL(k_lmk, dim3(816), dim3(256), 0, stream, outv, land, outl);
}